// Round 1
// baseline (377.622 us; speedup 1.0000x reference)
//
#include <hip/hip_runtime.h>

#define KK 64
#define TT 1024
#define BB 256
#define START_TAG 0

__device__ __forceinline__ float lane_bcast(float v, int lane) {
    return __int_as_float(__builtin_amdgcn_readlane(__float_as_int(v), lane));
}

// 64 named scalars for the exp(trans) row, PINNED into VGPRs with opaque asm
// so the compiler cannot rematerialize exp(load(trow[j])) inside the loop.
#define DECL4(p,q,r,s) \
    float et##p = __expf(trow[p]), et##q = __expf(trow[q]), \
          et##r = __expf(trow[r]), et##s = __expf(trow[s]);

#define PIN4(p,q,r,s) \
    asm volatile("" : "+v"(et##p), "+v"(et##q), "+v"(et##r), "+v"(et##s));

// j = 0..15: broadcast via v_readlane from the register copy of a.
// These have no dependence on the LDS write of the previous step, so they
// execute during the ds_write -> ds_read round-trip latency.
#define RL4(p,q,r,s) { \
    float bp = lane_bcast(av, p), bq = lane_bcast(av, q); \
    float br = lane_bcast(av, r), bs = lane_bcast(av, s); \
    acc0 = fmaf(et##p, bp, acc0); acc1 = fmaf(et##q, bq, acc1); \
    acc2 = fmaf(et##r, br, acc2); acc3 = fmaf(et##s, bs, acc3); }

// j = 16..63: broadcast via wave-uniform ds_read_b128 (4 values / instr,
// same-address broadcast = conflict-free).
#define LF4(g, p,q,r,s) { \
    acc0 = fmaf(et##p, w##g.x, acc0); acc1 = fmaf(et##q, w##g.y, acc1); \
    acc2 = fmaf(et##r, w##g.z, acc2); acc3 = fmaf(et##s, w##g.w, acc3); }

// One recurrence step. RB/WB are compile-time LDS double-buffer parities.
// EFV = exp(feat) (precomputed off the critical path), MKV = mask value,
// RN = literal 0/1: do the once-per-4-steps renorm before the store so the
// LDS copy and register copy stay identical.
#define DO_STEP_H(RB, WB, EFV, MKV, RN) { \
    const float4* rb4_ = reinterpret_cast<const float4*>(abuf[RB]); \
    float4 w4  = rb4_[4],  w5  = rb4_[5],  w6  = rb4_[6],  w7  = rb4_[7]; \
    float4 w8  = rb4_[8],  w9  = rb4_[9],  w10 = rb4_[10], w11 = rb4_[11]; \
    float4 w12 = rb4_[12], w13 = rb4_[13], w14 = rb4_[14], w15 = rb4_[15]; \
    float av = a; \
    float acc0 = 0.f, acc1 = 0.f, acc2 = 0.f, acc3 = 0.f; \
    RL4(0,1,2,3)        RL4(4,5,6,7)        RL4(8,9,10,11)      RL4(12,13,14,15)   \
    LF4(4, 16,17,18,19) LF4(5, 20,21,22,23) LF4(6, 24,25,26,27) LF4(7, 28,29,30,31) \
    LF4(8, 32,33,34,35) LF4(9, 36,37,38,39) LF4(10,40,41,42,43) LF4(11,44,45,46,47) \
    LF4(12,48,49,50,51) LF4(13,52,53,54,55) LF4(14,56,57,58,59) LF4(15,60,61,62,63) \
    float s_ = (acc0 + acc1) + (acc2 + acc3); \
    float anew = s_ * (EFV); \
    a = ((MKV) != 0.0f) ? anew : a; \
    if (RN) { \
        float a1 = fmaxf(lane_bcast(a, 1), 1e-37f); \
        a *= __builtin_amdgcn_rcpf(a1); \
        offset += __logf(a1); \
    } \
    abuf[WB][i] = a; \
}

// Forward algorithm in the probability domain. One wave per batch element;
// lane i owns state i and exp(trans[i,:]) in 64 pinned VGPRs. Broadcast of
// a[j]: j<16 via v_readlane (fills LDS round-trip latency), j>=16 via
// wave-uniform ds_read_b128 from a double-buffered LDS copy of a.
// Renorm once per 4 steps by a[1] (wave-uniform positive scale is exact via
// offset += log(scale)).
__global__ __launch_bounds__(64)
__attribute__((amdgpu_waves_per_eu(1, 1)))
void crf_forward_kernel(
    const float* __restrict__ feats,
    const float* __restrict__ trans,
    const float* __restrict__ masks,
    const int*   __restrict__ tags,
    float* __restrict__ out)
{
    const int b = blockIdx.x;
    const int i = threadIdx.x;

    __shared__ __align__(16) float abuf[2][KK];

    const float* trow = trans + i * KK;
    DECL4(0,1,2,3)     DECL4(4,5,6,7)     DECL4(8,9,10,11)   DECL4(12,13,14,15)
    DECL4(16,17,18,19) DECL4(20,21,22,23) DECL4(24,25,26,27) DECL4(28,29,30,31)
    DECL4(32,33,34,35) DECL4(36,37,38,39) DECL4(40,41,42,43) DECL4(44,45,46,47)
    DECL4(48,49,50,51) DECL4(52,53,54,55) DECL4(56,57,58,59) DECL4(60,61,62,63)
    PIN4(0,1,2,3)     PIN4(4,5,6,7)     PIN4(8,9,10,11)   PIN4(12,13,14,15)
    PIN4(16,17,18,19) PIN4(20,21,22,23) PIN4(24,25,26,27) PIN4(28,29,30,31)
    PIN4(32,33,34,35) PIN4(36,37,38,39) PIN4(40,41,42,43) PIN4(44,45,46,47)
    PIN4(48,49,50,51) PIN4(52,53,54,55) PIN4(56,57,58,59) PIN4(60,61,62,63)

    float a = (i == START_TAG) ? 1.0f : 0.0f;  // exp(alpha0)
    float offset = 0.0f;                        // running log-scale
    abuf[0][i] = a;                             // seed LDS copy (buffer 0)

    const float* fb = feats + (size_t)b * TT * KK;
    const float* mb = masks + (size_t)b * TT;

    // prologue prefetch: steps t = 1..4
    float cf0 = fb[1 * KK + i], cf1 = fb[2 * KK + i];
    float cf2 = fb[3 * KK + i], cf3 = fb[4 * KK + i];
    float cm0 = mb[1], cm1 = mb[2], cm2 = mb[3], cm3 = mb[4];

    // groups t0 = 1,5,...,1021; last group's 4th step (t=1024) masked off.
    // Per group: 4 steps with static LDS parities 0->1->0->1 (ends back at 0).
    for (int t0 = 1; t0 < TT; t0 += 4) {
        int p0 = (t0 + 4 < TT) ? t0 + 4 : TT - 1;
        int p1 = (t0 + 5 < TT) ? t0 + 5 : TT - 1;
        int p2 = (t0 + 6 < TT) ? t0 + 6 : TT - 1;
        int p3 = (t0 + 7 < TT) ? t0 + 7 : TT - 1;
        float nf0 = fb[p0 * KK + i], nf1 = fb[p1 * KK + i];
        float nf2 = fb[p2 * KK + i], nf3 = fb[p3 * KK + i];
        float nm0 = mb[p0], nm1 = mb[p1], nm2 = mb[p2], nm3 = mb[p3];

        // exp(feat) for the current group: inputs prefetched a full group
        // ago, so these v_exp ops are off the recurrence critical path.
        float ef0 = __expf(cf0), ef1 = __expf(cf1);
        float ef2 = __expf(cf2), ef3 = __expf(cf3);

        DO_STEP_H(0, 1, ef0, cm0, 0)
        DO_STEP_H(1, 0, ef1, cm1, 0)
        DO_STEP_H(0, 1, ef2, cm2, 0)
        float m3 = (t0 + 3 < TT) ? cm3 : 0.0f;   // only last group clips
        DO_STEP_H(1, 0, ef3, m3, 1)              // renorm folded into step 4

        cf0 = nf0; cf1 = nf1; cf2 = nf2; cf3 = nf3;
        cm0 = nm0; cm1 = nm1; cm2 = nm2; cm3 = nm3;
    }

    // forward_score = offset + log(sum_j a_j)
    float s = a;
    #pragma unroll
    for (int off = 32; off >= 1; off >>= 1)
        s += __shfl_xor(s, off, 64);
    float fwd_score = offset + __logf(s);

    // ---- fused gold score: sum_t (trans[ct,pt] + feats[t,ct]) * mask[t] ----
    const int* tg = tags + b * TT;
    float g = 0.f;
    for (int t = 1 + i; t < TT; t += 64) {
        int ct = tg[t], pt = tg[t - 1];
        g += (trans[ct * KK + pt] + fb[t * KK + ct]) * mb[t];
    }
    #pragma unroll
    for (int off = 32; off >= 1; off >>= 1)
        g += __shfl_xor(g, off, 64);

    if (i == 0) atomicAdd(out, (fwd_score - g) * (1.0f / (float)BB));
}

extern "C" void kernel_launch(void* const* d_in, const int* in_sizes, int n_in,
                              void* d_out, int out_size, void* d_ws, size_t ws_size,
                              hipStream_t stream) {
    const float* feats = (const float*)d_in[0];
    const float* trans = (const float*)d_in[1];
    const int*   tags  = (const int*)d_in[2];
    const float* masks = (const float*)d_in[3];
    float* out = (float*)d_out;

    hipMemsetAsync(out, 0, sizeof(float), stream);  // atomicAdd accumulator
    crf_forward_kernel<<<BB, 64, 0, stream>>>(feats, trans, masks, tags, out);
}

// Round 2
// 348.682 us; speedup vs baseline: 1.0830x; 1.0830x over previous
//
#include <hip/hip_runtime.h>

#define KK 64
#define TT 1024
#define BB 256
#define START_TAG 0

// 16 named scalars for this lane's slice of the exp(trans) row, PINNED into
// VGPRs with opaque asm so the compiler cannot rematerialize exp(load()).
#define DECL4(p,q,r,s) \
    float et##p = __expf(trow[p]), et##q = __expf(trow[q]), \
          et##r = __expf(trow[r]), et##s = __expf(trow[s]);

#define PIN4(p,q,r,s) \
    asm volatile("" : "+v"(et##p), "+v"(et##q), "+v"(et##r), "+v"(et##s));

// One recurrence step, split across 4 waves.
// Lane l of wave wid: output state i = 16*wid + (l&15), j-quarter jg = l>>4.
//  1. 4x ds_read_b128 of this lane's j-quarter of a[] (2-way bank alias = free)
//  2. 16 FMAs on 4 independent chains -> 16-term partial
//  3. shfl_xor(16) + shfl_xor(32): sum the 4 j-quarters (full a_new in all lanes)
//  4. * exp(feat), mask select, optional once-per-4-steps renorm by a[1]
//  5. jg==0 lanes write this wave's 16-state slice to the alternate buffer
//  6. s_waitcnt lgkmcnt(0) + raw s_barrier  (NO vmcnt drain: feats prefetch
//     stays in flight across barriers; only LDS visibility is needed)
// RB/WB are compile-time double-buffer parities. Single barrier per step is
// safe: the lgkmcnt(0) drain means every wave's reads of buffer RB completed
// before it passes the barrier, and writes to RB only happen after the next
// barrier.
#define DO_STEP(RB, WB, EFV, MKV, RN) { \
    const float4* rb4_ = reinterpret_cast<const float4*>(abuf[RB] + (jg << 4)); \
    float4 q0 = rb4_[0], q1 = rb4_[1], q2 = rb4_[2], q3 = rb4_[3]; \
    float rn_a1 = 0.0f; \
    if (RN) rn_a1 = abuf[RB][1];   /* wave-uniform broadcast read */ \
    float acc0 = 0.f, acc1 = 0.f, acc2 = 0.f, acc3 = 0.f; \
    acc0 = fmaf(et0,  q0.x, acc0); acc1 = fmaf(et1,  q0.y, acc1); \
    acc2 = fmaf(et2,  q0.z, acc2); acc3 = fmaf(et3,  q0.w, acc3); \
    acc0 = fmaf(et4,  q1.x, acc0); acc1 = fmaf(et5,  q1.y, acc1); \
    acc2 = fmaf(et6,  q1.z, acc2); acc3 = fmaf(et7,  q1.w, acc3); \
    acc0 = fmaf(et8,  q2.x, acc0); acc1 = fmaf(et9,  q2.y, acc1); \
    acc2 = fmaf(et10, q2.z, acc2); acc3 = fmaf(et11, q2.w, acc3); \
    acc0 = fmaf(et12, q3.x, acc0); acc1 = fmaf(et13, q3.y, acc1); \
    acc2 = fmaf(et14, q3.z, acc2); acc3 = fmaf(et15, q3.w, acc3); \
    float p_ = (acc0 + acc1) + (acc2 + acc3); \
    p_ += __shfl_xor(p_, 16, 64); \
    p_ += __shfl_xor(p_, 32, 64); \
    float anew = p_ * (EFV); \
    a = ((MKV) != 0.0f) ? anew : a; \
    if (RN) { \
        float a1 = fmaxf(rn_a1, 1e-37f); \
        a *= __builtin_amdgcn_rcpf(a1); \
        offset += __logf(a1); \
    } \
    if (jg == 0) abuf[WB][i] = a; \
    asm volatile("s_waitcnt lgkmcnt(0)" ::: "memory"); \
    __builtin_amdgcn_s_barrier(); \
}

// Forward algorithm in the probability domain, 4 waves per batch element.
// Renorm once per 4 steps by a[1] read from the step's source buffer
// (wave-uniform positive scale is exact via offset += log(scale); applied
// after the mask select so masked steps scale consistently).
__global__ __launch_bounds__(256)
__attribute__((amdgpu_waves_per_eu(1, 1)))
void crf_forward_kernel(
    const float* __restrict__ feats,
    const float* __restrict__ trans,
    const float* __restrict__ masks,
    const int*   __restrict__ tags,
    float* __restrict__ out)
{
    const int b   = blockIdx.x;
    const int tid = threadIdx.x;
    const int wid = tid >> 6;          // wave 0..3
    const int l   = tid & 63;          // lane
    const int il  = l & 15;            // local output index
    const int jg  = l >> 4;            // j-quarter 0..3
    const int i   = (wid << 4) | il;   // output state this lane computes

    __shared__ __align__(16) float abuf[2][KK];
    __shared__ float spart[4], gpart[4];

    // et[k] = exp(trans[i][16*jg + k]), k = 0..15
    const float* trow = trans + i * KK + (jg << 4);
    DECL4(0,1,2,3) DECL4(4,5,6,7) DECL4(8,9,10,11) DECL4(12,13,14,15)
    PIN4(0,1,2,3)  PIN4(4,5,6,7)  PIN4(8,9,10,11)  PIN4(12,13,14,15)

    float a = (i == START_TAG) ? 1.0f : 0.0f;  // exp(alpha0), replicated per jg
    float offset = 0.0f;                        // running log-scale

    if (tid < KK) abuf[0][tid] = (tid == START_TAG) ? 1.0f : 0.0f;
    __syncthreads();

    const float* fb = feats + (size_t)b * TT * KK;
    const float* mb = masks + (size_t)b * TT;

    // prologue prefetch: steps t = 1..4
    float cf0 = fb[1 * KK + i], cf1 = fb[2 * KK + i];
    float cf2 = fb[3 * KK + i], cf3 = fb[4 * KK + i];
    float cm0 = mb[1], cm1 = mb[2], cm2 = mb[3], cm3 = mb[4];

    // groups t0 = 1,5,...,1021; last group's 4th step (t=1024) masked off.
    // Parities per group: 0->1->0->1 (even length, every group starts at 0).
    for (int t0 = 1; t0 < TT; t0 += 4) {
        int p0 = (t0 + 4 < TT) ? t0 + 4 : TT - 1;
        int p1 = (t0 + 5 < TT) ? t0 + 5 : TT - 1;
        int p2 = (t0 + 6 < TT) ? t0 + 6 : TT - 1;
        int p3 = (t0 + 7 < TT) ? t0 + 7 : TT - 1;
        float nf0 = fb[p0 * KK + i], nf1 = fb[p1 * KK + i];
        float nf2 = fb[p2 * KK + i], nf3 = fb[p3 * KK + i];
        float nm0 = mb[p0], nm1 = mb[p1], nm2 = mb[p2], nm3 = mb[p3];

        // exp(feat): inputs prefetched a full group ago -> off critical path
        float ef0 = __expf(cf0), ef1 = __expf(cf1);
        float ef2 = __expf(cf2), ef3 = __expf(cf3);

        DO_STEP(0, 1, ef0, cm0, 0)
        DO_STEP(1, 0, ef1, cm1, 0)
        DO_STEP(0, 1, ef2, cm2, 0)
        float m3 = (t0 + 3 < TT) ? cm3 : 0.0f;   // only last group clips
        DO_STEP(1, 0, ef3, m3, 1)                // renorm folded into step 4

        cf0 = nf0; cf1 = nf1; cf2 = nf2; cf3 = nf3;
        cm0 = nm0; cm1 = nm1; cm2 = nm2; cm3 = nm3;
    }

    // wave-local sum of final a: full 64-lane reduce counts each state 4x
    // (jg replicas), so scale by 0.25.
    float s = a;
    #pragma unroll
    for (int off = 32; off >= 1; off >>= 1)
        s += __shfl_xor(s, off, 64);
    s *= 0.25f;
    if (l == 0) spart[wid] = s;

    // ---- fused gold score over all 256 threads ----
    const int* tg = tags + b * TT;
    float g = 0.f;
    for (int t = 1 + tid; t < TT; t += 256) {
        int ct = tg[t], pt = tg[t - 1];
        g += (trans[ct * KK + pt] + fb[t * KK + ct]) * mb[t];
    }
    #pragma unroll
    for (int off = 32; off >= 1; off >>= 1)
        g += __shfl_xor(g, off, 64);
    if (l == 0) gpart[wid] = g;

    __syncthreads();
    if (tid == 0) {
        float S = spart[0] + spart[1] + spart[2] + spart[3];
        float G = gpart[0] + gpart[1] + gpart[2] + gpart[3];
        float fwd_score = offset + __logf(S);
        atomicAdd(out, (fwd_score - G) * (1.0f / (float)BB));
    }
}

extern "C" void kernel_launch(void* const* d_in, const int* in_sizes, int n_in,
                              void* d_out, int out_size, void* d_ws, size_t ws_size,
                              hipStream_t stream) {
    const float* feats = (const float*)d_in[0];
    const float* trans = (const float*)d_in[1];
    const int*   tags  = (const int*)d_in[2];
    const float* masks = (const float*)d_in[3];
    float* out = (float*)d_out;

    hipMemsetAsync(out, 0, sizeof(float), stream);  // atomicAdd accumulator
    crf_forward_kernel<<<BB, 256, 0, stream>>>(feats, trans, masks, tags, out);
}